// Round 8
// baseline (3840.465 us; speedup 1.0000x reference)
//
#include <hip/hip_runtime.h>
#include <hip/hip_bf16.h>
#include <stdint.h>

// Sparse autoencoder: z1 = x@W^T + b_enc ; top-k(3276) mask ; z2 = a1@W + b_dec
// Encoder = single bf16 MFMA GEMM (approx, sigma ~1.6e-3); exact top-k
// selection via fp32 band recompute near the threshold (h-major).
// GEMMs: 256^2 tile, 8-phase m201-derived schedule: UNIFORM 1 half-tile
// (2 global_load_lds) staged EVERY phase, vmcnt(6) at ph4/ph8 (3-half residual),
// zigzag frag reads held in regs, T2 swizzle, no explicit lgkm waits.

#define DIM      4096
#define BATCH    4096
#define NROWS_W  32768
#define KCNT     3276
#define DELTA    0.0066f
#define ROWCAP   256
#define HCAP     64
#define CANDCAP  3584

typedef __bf16 bf16x8 __attribute__((ext_vector_type(8)));
typedef __bf16 bf16x4 __attribute__((ext_vector_type(4)));
typedef float  f32x4  __attribute__((ext_vector_type(4)));

__device__ __forceinline__ void gload_lds16(const void* g, void* l) {
  __builtin_amdgcn_global_load_lds(
      (const __attribute__((address_space(1))) void*)g,
      (__attribute__((address_space(3))) void*)l, 16, 0, 0);
}

// ---------------- split x: fp32 -> bf16 hi + bf16 lo ----------------
__global__ void k_split(const float* __restrict__ s, __bf16* __restrict__ hi,
                        __bf16* __restrict__ lo, int n4) {
  int i = blockIdx.x * 256 + threadIdx.x;
  const int stride = gridDim.x * 256;
  for (; i < n4; i += stride) {
    f32x4 v = ((const f32x4*)s)[i];
    bf16x4 h, l;
#pragma unroll
    for (int j = 0; j < 4; ++j) {
      __bf16 hb = (__bf16)v[j];
      h[j] = hb;
      l[j] = (__bf16)(v[j] - (float)hb);
    }
    ((bf16x4*)hi)[i] = h;
    ((bf16x4*)lo)[i] = l;
  }
}

// ------- fused W split+transpose: W fp32 -> Wh bf16 [H,D] + Wt bf16 [D,H] ----
__global__ void k_splitw(const float* __restrict__ W, __bf16* __restrict__ Wh,
                         __bf16* __restrict__ Wt) {
  __shared__ __bf16 t[64][65];
  const int c0 = blockIdx.x * 64, r0 = blockIdx.y * 64;
  const int tx = threadIdx.x, ty = threadIdx.y;  // (64, 8)
  for (int rr = ty; rr < 64; rr += 8) {
    const float w = W[(long)(r0 + rr) * DIM + c0 + tx];
    const __bf16 h = (__bf16)w;
    Wh[(long)(r0 + rr) * DIM + c0 + tx] = h;
    t[rr][tx] = h;
  }
  __syncthreads();
  for (int cc = ty; cc < 64; cc += 8)
    Wt[(long)(c0 + cc) * NROWS_W + r0 + tx] = t[tx][cc];
}

// =============== 256x256 8-phase GEMM (uniform-stage schedule) ===============
// 8 waves 2(M) x 4(N); wave out 128x64. K-tiles T0=2i (buf0), T1=2i+1 (buf1).
// Stage exactly one 16KB half (2 gload calls) per phase:
//  ph1:A1(T1)->b1  ph2:A0(T2)->b0  ph3:B0(T2)->b0  ph4:B1(T2)->b0 +vmcnt(6)
//  ph5:A1(T2)->b0  ph6:A0(T3)->b1  ph7:B0(T3)->b1  ph8:B1(T3)->b1 +vmcnt(6)
// Reads (zigzag, frags held): ph1:A0+B0(12) ph2:B1(4) ph3:A1(8) ph4:none.
// Ledger verified: every overwrite >=2 phases after victim's last-read barrier;
// every stage confirmed by a vmcnt(6) before its first read; residual = 3 halves.

#define VMW6 asm volatile("s_waitcnt vmcnt(6)" ::: "memory")
#define BAR  __builtin_amdgcn_s_barrier()

#define RD_A(CUR, QM)                                                          \
  _Pragma("unroll") for (int m_ = 0; m_ < 4; ++m_) {                           \
    const int row_ = (QM) * 128 + wm * 64 + m_ * 16 + lr;                      \
    _Pragma("unroll") for (int kc_ = 0; kc_ < 2; ++kc_)                        \
      af[m_][kc_] = *(const bf16x8*)((const char*)sA[CUR] + row_ * 128 +       \
                                     ((kc_ * 64 + lk * 16) ^ swz));            \
  }
#define RD_B(CUR, QN, BF)                                                      \
  _Pragma("unroll") for (int n_ = 0; n_ < 2; ++n_) {                           \
    const int col_ = (QN) * 128 + wn * 32 + n_ * 16 + lr;                      \
    _Pragma("unroll") for (int kc_ = 0; kc_ < 2; ++kc_)                        \
      BF[n_][kc_] = *(const bf16x8*)((const char*)sB[CUR] + col_ * 128 +       \
                                     ((kc_ * 64 + lk * 16) ^ swz));            \
  }
#define MM(QM, QN, BF)                                                         \
  __builtin_amdgcn_s_setprio(1);                                               \
  _Pragma("unroll") for (int m_ = 0; m_ < 4; ++m_)                             \
    _Pragma("unroll") for (int n_ = 0; n_ < 2; ++n_)                           \
      _Pragma("unroll") for (int kc_ = 0; kc_ < 2; ++kc_)                      \
        acc[(QM) * 4 + m_][(QN) * 2 + n_] =                                    \
            __builtin_amdgcn_mfma_f32_16x16x32_bf16(                           \
                af[m_][kc_], BF[n_][kc_],                                      \
                acc[(QM) * 4 + m_][(QN) * 2 + n_], 0, 0, 0);                   \
  __builtin_amdgcn_s_setprio(0);

#define ITER8(KB1, KB2, KB3)                                                   \
  /* ph1 */ RD_A(0, 0) RD_B(0, 0, bf0)                                         \
  stA(1, 1, 0, KB1); stA(1, 1, 1, KB1);                                        \
  BAR; MM(0, 0, bf0) BAR;                                                      \
  /* ph2 */ RD_B(0, 1, bf1)                                                    \
  stA(0, 0, 0, KB2); stA(0, 0, 1, KB2);                                        \
  BAR; MM(0, 1, bf1) BAR;                                                      \
  /* ph3 */ RD_A(0, 1)                                                         \
  stB(0, 0, 0, KB2); stB(0, 0, 1, KB2);                                        \
  BAR; MM(1, 1, bf1) BAR;                                                      \
  /* ph4 */ stB(0, 1, 0, KB2); stB(0, 1, 1, KB2);                              \
  BAR; MM(1, 0, bf0) VMW6; BAR;                                                \
  /* ph5 */ RD_A(1, 0) RD_B(1, 0, bf0)                                         \
  stA(0, 1, 0, KB2); stA(0, 1, 1, KB2);                                        \
  BAR; MM(0, 0, bf0) BAR;                                                      \
  /* ph6 */ RD_B(1, 1, bf1)                                                    \
  stA(1, 0, 0, KB3); stA(1, 0, 1, KB3);                                        \
  BAR; MM(0, 1, bf1) BAR;                                                      \
  /* ph7 */ RD_A(1, 1)                                                         \
  stB(1, 0, 0, KB3); stB(1, 0, 1, KB3);                                        \
  BAR; MM(1, 1, bf1) BAR;                                                      \
  /* ph8 */ stB(1, 1, 0, KB3); stB(1, 1, 1, KB3);                              \
  BAR; MM(1, 0, bf0) VMW6; BAR;

template <int MT, int NTOT, int KT>
__global__ __launch_bounds__(512, 2)
void k_gemm256(const __bf16* __restrict__ A, const __bf16* __restrict__ B,
               const float* __restrict__ bias, float* __restrict__ C) {
  __shared__ __align__(16) __bf16 sA[2][256 * 64];
  __shared__ __align__(16) __bf16 sB[2][256 * 64];

  const int tid = threadIdx.x;
  constexpr int nbm = MT / 256, nbn = NTOT / 256;
  int wg = blockIdx.x;
  { const int c = (nbm * nbn) >> 3; wg = (wg & 7) * c + (wg >> 3); }
  int bm, bn;
  if constexpr (nbm % 4 == 0 && nbn % 16 == 0) {
    constexpr int nstn = nbn / 16;
    const int st = wg >> 6, r = wg & 63;
    bm = (st / nstn) * 4 + (r >> 4);
    bn = (st % nstn) * 16 + (r & 15);
  } else {
    bm = wg / nbn; bn = wg % nbn;
  }
  const long m0 = (long)bm * 256, n0 = (long)bn * 256;

  const int lane = tid & 63, wid = tid >> 6;
  const int wm = wid >> 2, wn = wid & 3;      // 2 x 4 waves
  const int lr = lane & 15, lk = lane >> 4;
  const int swz = (lr & 7) << 4;

  // u (0/1) = 128-row/col half; c (0/1) = 8KB sub-call (64 rows/cols)
  auto stA = [&](int buf, int u, int c, long kb) {
    const int o = tid * 16;
    const int colb = (o & 127) ^ (((o >> 7) & 7) << 4);
    const long row = m0 + u * 128 + c * 64 + (o >> 7);
    gload_lds16((const char*)A + row * (KT * 2) + kb + colb,
                (char*)sA[buf] + u * 16384 + c * 8192 + o);
  };
  auto stB = [&](int buf, int u, int c, long kb) {
    const int o = tid * 16;
    const int colb = (o & 127) ^ (((o >> 7) & 7) << 4);
    const long col = n0 + u * 128 + c * 64 + (o >> 7);
    gload_lds16((const char*)B + col * (KT * 2) + kb + colb,
                (char*)sB[buf] + u * 16384 + c * 8192 + o);
  };

  f32x4 acc[8][4] = {};
  bf16x8 af[4][2], bf0[2][2], bf1[2][2];

  // prologue: tile0 {A0,B0,B1,A1}->buf0, tile1 {A0,B0,B1}->buf1 (A1(1) at ph1)
  stA(0, 0, 0, 0); stA(0, 0, 1, 0);
  stB(0, 0, 0, 0); stB(0, 0, 1, 0);
  stB(0, 1, 0, 0); stB(0, 1, 1, 0);
  stA(0, 1, 0, 0); stA(0, 1, 1, 0);
  stA(1, 0, 0, 128); stA(1, 0, 1, 128);
  stB(1, 0, 0, 128); stB(1, 0, 1, 128);
  stB(1, 1, 0, 128); stB(1, 1, 1, 128);
  VMW6;  // confirms exactly tile0's 4 halves; residual = tile1's 3 halves
  BAR;

  constexpr int NT = KT / 64;
  for (int i = 0; i < NT / 2; ++i) {
    const long kb1 = (long)(2 * i + 1) * 128;
    const long kb2 = (2 * i + 2 < NT) ? (long)(2 * i + 2) * 128 : 0;
    const long kb3 = (2 * i + 3 < NT) ? (long)(2 * i + 3) * 128 : 0;
    ITER8(kb1, kb2, kb3)
  }
  asm volatile("s_waitcnt vmcnt(0)" ::: "memory");

  // C/D layout: col = lane&15, row = (lane>>4)*4 + reg
#pragma unroll
  for (int nf = 0; nf < 4; ++nf) {
    const int qn = nf >> 1, nn = nf & 1;
    const long col = n0 + qn * 128 + wn * 32 + nn * 16 + lr;
    const float bv = bias[col];
#pragma unroll
    for (int mf = 0; mf < 8; ++mf) {
      const int qm = mf >> 2, mm = mf & 3;
      const long r0r = m0 + qm * 128 + wm * 64 + mm * 16 + lk * 4;
#pragma unroll
      for (int j = 0; j < 4; ++j)
        C[(r0r + j) * NTOT + col] = acc[mf][nf][j] + bv;
    }
  }
}

// ---------------- float <-> order-preserving u32 ----------------
__device__ __forceinline__ unsigned f2o(float f) {
  unsigned b = __float_as_uint(f);
  return ((int)b < 0) ? ~b : (b | 0x80000000u);
}
__device__ __forceinline__ float o2f(unsigned u) {
  unsigned b = (u & 0x80000000u) ? (u & 0x7FFFFFFFu) : ~u;
  return __uint_as_float(b);
}

// --- per-row: threshold (2 z1 streams) + band from cand list + a1 write ------
// pass A: 4096-bin hist; pass B: collect (v,idx) for bins binsel-1..binsel+1
// (bin width ~0.16 >> DELTA so band is inside); in-LDS 20-bit refine -> t;
// band filter from cand list; pass C: write a1 sure-ins + count c1.
__global__ __launch_bounds__(256)
void k_topk4(const float* __restrict__ z1, float* __restrict__ thr,
             unsigned* __restrict__ rowlist, unsigned* __restrict__ rowcnt,
             unsigned* __restrict__ c1, unsigned* __restrict__ bucket,
             unsigned* __restrict__ bcnt, __bf16* __restrict__ a1, int kwant) {
  __shared__ unsigned hist[4096];
  __shared__ float cv[CANDCAP];
  __shared__ unsigned short ci[CANDCAP];
  __shared__ unsigned s_n, s_bin, s_rem, s_wt[4], s_cnt, s_above;
  const int tid = threadIdx.x;
  const int b = blockIdx.x;
  const f32x4* zv = (const f32x4*)(z1 + (long)b * NROWS_W);
  constexpr int NV = NROWS_W / 4;

  // ---- pass A ----
#pragma unroll
  for (int j = 0; j < 16; ++j) hist[tid + j * 256] = 0;
  if (tid == 0) { s_n = 0; s_cnt = 0; s_above = 0; }
  __syncthreads();
  for (int i = tid; i < NV; i += 256) {
    f32x4 v = zv[i];
#pragma unroll
    for (int j = 0; j < 4; ++j) atomicAdd(&hist[f2o(v[j]) >> 20], 1u);
  }
  __syncthreads();
  unsigned p = 0;
#pragma unroll
  for (int j = 0; j < 16; ++j) p += hist[tid * 16 + j];
  unsigned sfx = p;
  const int lane = tid & 63, w = tid >> 6;
#pragma unroll
  for (int off = 1; off < 64; off <<= 1) {
    unsigned o = __shfl_down(sfx, off);
    sfx += (lane + off < 64) ? o : 0u;
  }
  if (lane == 0) s_wt[w] = sfx;
  __syncthreads();
  unsigned above_waves = 0;
  for (int ww = w + 1; ww < 4; ++ww) above_waves += s_wt[ww];
  const unsigned incl = sfx + above_waves;
  const int cnt = __syncthreads_count(incl >= (unsigned)kwant);
  const int tstar = cnt - 1;
  if (tid == tstar) {
    unsigned cum = incl - p;
    int bsel = tid * 16;
    for (int j = 15; j >= 0; --j) {
      const unsigned h = hist[tid * 16 + j];
      if (cum + h >= (unsigned)kwant) { bsel = tid * 16 + j; break; }
      cum += h;
    }
    s_bin = (unsigned)bsel;
    s_rem = (unsigned)kwant - cum;
  }
  __syncthreads();
  const unsigned binsel = s_bin;
  unsigned rem = s_rem;

  // ---- pass B: collect bins binsel-1..binsel+1 with indices ----
  const unsigned blo = (binsel > 0) ? binsel - 1 : 0;
  const unsigned bhi = (binsel < 4095) ? binsel + 1 : 4095;
  for (int i = tid; i < NV; i += 256) {
    f32x4 v = zv[i];
#pragma unroll
    for (int j = 0; j < 4; ++j) {
      const unsigned bin = f2o(v[j]) >> 20;
      if (bin >= blo && bin <= bhi) {
        const unsigned jj = atomicAdd(&s_n, 1u);
        if (jj < CANDCAP) { cv[jj] = v[j]; ci[jj] = (unsigned short)(i * 4 + j); }
      }
    }
  }
  __syncthreads();
  const int n = (s_n < CANDCAP) ? (int)s_n : CANDCAP;

  // ---- in-LDS 20-bit refine over cand members of binsel ----
  unsigned pfx = 0;
#pragma unroll
  for (int pass = 0; pass < 3; ++pass) {
    const int shift = (pass == 0) ? 12 : (pass == 1) ? 4 : 0;
    const int nb = (pass == 2) ? 16 : 256;
    if (tid < 256) hist[tid] = 0;
    __syncthreads();
    for (int i = tid; i < n; i += 256) {
      const unsigned u = f2o(cv[i]);
      if ((u >> 20) != binsel) continue;
      const unsigned v = u & 0xFFFFFu;
      const bool m = (pass == 0) ? true
                     : (pass == 1) ? ((v >> 12) == (pfx >> 12))
                                   : ((v >> 4) == (pfx >> 4));
      if (m) atomicAdd(&hist[(v >> shift) & (nb - 1)], 1u);
    }
    __syncthreads();
    if (tid == 0) {
      unsigned cum = 0;
      int d = nb - 1;
      for (; d > 0; --d) {
        if (cum + hist[d] >= rem) break;
        cum += hist[d];
      }
      s_bin = (unsigned)d;
      s_rem = rem - cum;
    }
    __syncthreads();
    pfx |= (s_bin << shift);
    rem = s_rem;
    __syncthreads();
  }
  const float t = o2f((binsel << 20) | pfx);
  if (tid == 0) thr[b] = t;
  const float hi = t + DELTA, lo = t - DELTA;

  // ---- band members from cand list (no z1 re-scan) ----
  for (int i = tid; i < n; i += 256) {
    const float v = cv[i];
    if (v >= lo && v <= hi) {
      const unsigned idx = ci[i];
      const unsigned jj = atomicAdd(&s_cnt, 1u);
      if (jj < ROWCAP) {
        rowlist[(long)b * ROWCAP + jj] = idx;
        const unsigned pq = atomicAdd(&bcnt[idx], 1u);
        if (pq < HCAP) bucket[(long)idx * HCAP + pq] = ((unsigned)b << 9) | jj;
      }
    }
  }

  // ---- pass C: write a1 (sure-ins only; band patched by k_select), count c1 --
  unsigned my_above = 0;
  bf16x4* av = (bf16x4*)(a1 + (long)b * NROWS_W);
  for (int i = tid; i < NV; i += 256) {
    f32x4 v = zv[i];
    bf16x4 o;
#pragma unroll
    for (int j = 0; j < 4; ++j) {
      const bool in = v[j] > hi;
      my_above += in ? 1u : 0u;
      o[j] = in ? (__bf16)v[j] : (__bf16)0.0f;
    }
    av[i] = o;
  }
  atomicAdd(&s_above, my_above);
  __syncthreads();
  if (tid == 0) {
    rowcnt[b] = (s_cnt < ROWCAP) ? s_cnt : ROWCAP;
    c1[b] = s_above;
  }
}

// ---------------- zero bcnt ----------------
__global__ void k_zero(f32x4* __restrict__ p, int nvec) {
  int i = blockIdx.x * 256 + threadIdx.x;
  if (i < nvec) {
    f32x4 z = {0.f, 0.f, 0.f, 0.f};
    p[i] = z;
  }
}

// -------- h-major exact recompute: fp32 W row in LDS, x from hi+lo ----------
__global__ void k_recompute(const float* __restrict__ W, const __bf16* __restrict__ xh,
                            const __bf16* __restrict__ xl,
                            const unsigned* __restrict__ bucket,
                            const unsigned* __restrict__ bcnt,
                            float* __restrict__ exact) {
  const int h = blockIdx.x;
  unsigned n = bcnt[h];
  if (n > HCAP) n = HCAP;
  if (n == 0) return;
  __shared__ float wrec[DIM];
  const long wb = (long)h * DIM;
  for (int i = threadIdx.x; i < DIM / 4; i += 256)
    ((f32x4*)wrec)[i] = ((const f32x4*)(W + wb))[i];
  __syncthreads();
  const int w = threadIdx.x >> 6, lane = threadIdx.x & 63;
  for (unsigned e = w; e < n; e += 4) {
    const unsigned ent = bucket[(long)h * HCAP + e];
    const int b = ent >> 9, j = ent & 511;
    const bf16x8* ph = (const bf16x8*)(xh + (long)b * DIM);
    const bf16x8* pl = (const bf16x8*)(xl + (long)b * DIM);
    float s = 0.f;
#pragma unroll
    for (int c = 0; c < 8; ++c) {
      const int i8 = c * 64 + lane;
      bf16x8 vh = ph[i8], vl = pl[i8];
      const float* wr = &wrec[i8 * 8];
#pragma unroll
      for (int q = 0; q < 8; ++q) s += ((float)vh[q] + (float)vl[q]) * wr[q];
    }
#pragma unroll
    for (int m = 32; m; m >>= 1) s += __shfl_xor(s, m);
    if (lane == 0) exact[(long)b * ROWCAP + j] = s;
  }
}

// -- per-row select top (k - C1) among band; patch selected into a1 ----------
__global__ void k_select(const float* __restrict__ exact, const unsigned* __restrict__ rowlist,
                         const unsigned* __restrict__ rowcnt, const unsigned* __restrict__ c1,
                         const float* __restrict__ z1, __bf16* __restrict__ a1) {
  const int b = blockIdx.x;
  const int n = (int)rowcnt[b];
  const int need = KCNT - (int)c1[b];
  __shared__ float vals[ROWCAP];
  const int j = threadIdx.x;  // blockDim == ROWCAP
  vals[j] = (j < n) ? exact[(long)b * ROWCAP + j] : -1e30f;
  __syncthreads();
  if (j < n) {
    const float vj = vals[j];
    int rank = 0;
    for (int i = 0; i < n; ++i) {
      const float vi = vals[i];
      rank += (vi > vj || (vi == vj && i < j)) ? 1 : 0;
    }
    if (rank < need) {
      const unsigned h = rowlist[(long)b * ROWCAP + j];
      const long off = (long)b * NROWS_W + h;
      a1[off] = (__bf16)z1[off];
    }
  }
}

extern "C" void kernel_launch(void* const* d_in, const int* in_sizes, int n_in,
                              void* d_out, int out_size, void* d_ws, size_t ws_size,
                              hipStream_t stream) {
  const float* x     = (const float*)d_in[0];
  const float* W     = (const float*)d_in[1];
  const float* b_enc = (const float*)d_in[2];
  const float* b_dec = (const float*)d_in[3];
  float* out = (float*)d_out;

  const long NW = (long)NROWS_W * DIM;    // 134217728
  const long NX = (long)BATCH * DIM;      // 16777216
  const long NZ = (long)BATCH * NROWS_W;  // 134217728

  char* ws = (char*)d_ws;
  __bf16* Wh = (__bf16*)ws;        // 2*NW  (dead after encoder -> reused as a1)
  __bf16* Wt = Wh + NW;            // 2*NW
  __bf16* xh = Wt + NW;            // 2*NX
  __bf16* xl = xh + NX;            // 2*NX
  float*  z1 = (float*)(xl + NX);  // 4*NZ
  float*  thr = z1 + NZ;           // 4*BATCH
  char*   sc = (char*)(thr + BATCH);
  unsigned* rowcnt  = (unsigned*)sc;                    // 16 KB
  unsigned* c1      = (unsigned*)(sc + 16384);          // 16 KB
  unsigned* bcnt    = (unsigned*)(sc + 32768);          // 128 KB (zeroed)
  float*    exact   = (float*)(sc + 163840);            // 4 MB
  unsigned* rowlist = (unsigned*)(sc + 4358144);        // 4 MB
  unsigned* bucket  = (unsigned*)(sc + 8552448);        // 8 MB (end ~16.9 MB)
  __bf16* a1 = Wh;

  const size_t needed = (size_t)(6 * NW + 4 * NX) + (size_t)4 * NZ + 4 * BATCH;
  if (ws_size < needed) return;

  k_splitw<<<dim3(DIM / 64, NROWS_W / 64), dim3(64, 8), 0, stream>>>(W, Wh, Wt);
  k_split<<<2048, 256, 0, stream>>>(x, xh, xl, (int)(NX / 4));

  // encoder (approx): z1 = xh @ Wh^T + b_enc   [4096 x 32768]
  k_gemm256<BATCH, NROWS_W, DIM><<<(BATCH / 256) * (NROWS_W / 256), 512, 0, stream>>>(
      xh, Wh, b_enc, z1);

  k_zero<<<32, 256, 0, stream>>>((f32x4*)bcnt, 131072 / 16);
  k_topk4<<<BATCH, 256, 0, stream>>>(z1, thr, rowlist, rowcnt, c1, bucket, bcnt, a1, KCNT);
  k_recompute<<<NROWS_W, 256, 0, stream>>>(W, xh, xl, bucket, bcnt, exact);
  k_select<<<BATCH, ROWCAP, 0, stream>>>(exact, rowlist, rowcnt, c1, z1, a1);

  // decoder: out = a1 @ W + b_dec  (B^T = Wt)
  k_gemm256<BATCH, DIM, NROWS_W><<<(BATCH / 256) * (DIM / 256), 512, 0, stream>>>(
      a1, Wt, b_dec, out);
}

// Round 9
// 3552.748 us; speedup vs baseline: 1.0810x; 1.0810x over previous
//
#include <hip/hip_runtime.h>
#include <hip/hip_bf16.h>
#include <stdint.h>

// Sparse autoencoder: z1 = x@W^T + b_enc ; top-k(3276) mask ; z2 = a1@W + b_dec
// Encoder = single bf16 MFMA GEMM (approx, sigma ~1.6e-3); exact top-k
// selection via fp32 band recompute near the threshold (h-major, W streamed
// once, fp32 x L3-resident). GEMMs: proven 128^2 m97-structure + T2 swizzle
// + 16x32 supertile remap (R3/R7 — four 8-phase variants all measured slower).

#define DIM      4096
#define BATCH    4096
#define NROWS_W  32768
#define KCNT     3276
#define DELTA    0.0066f
#define ROWCAP   256
#define HCAP     64
#define CANDCAP  3584

typedef __bf16 bf16x8 __attribute__((ext_vector_type(8)));
typedef __bf16 bf16x4 __attribute__((ext_vector_type(4)));
typedef float  f32x4  __attribute__((ext_vector_type(4)));

__device__ __forceinline__ void gload_lds16(const void* g, void* l) {
  __builtin_amdgcn_global_load_lds(
      (const __attribute__((address_space(1))) void*)g,
      (__attribute__((address_space(3))) void*)l, 16, 0, 0);
}

// ---------------- x: fp32 -> bf16 (encoder A operand) ----------------
__global__ void k_cvtx(const float* __restrict__ s, __bf16* __restrict__ hi, int n4) {
  int i = blockIdx.x * 256 + threadIdx.x;
  const int stride = gridDim.x * 256;
  for (; i < n4; i += stride) {
    f32x4 v = ((const f32x4*)s)[i];
    bf16x4 h;
#pragma unroll
    for (int j = 0; j < 4; ++j) h[j] = (__bf16)v[j];
    ((bf16x4*)hi)[i] = h;
  }
}

// ------- fused W split+transpose: W fp32 -> Wh bf16 [H,D] + Wt bf16 [D,H] ----
__global__ void k_splitw(const float* __restrict__ W, __bf16* __restrict__ Wh,
                         __bf16* __restrict__ Wt) {
  __shared__ __bf16 t[64][65];
  const int c0 = blockIdx.x * 64, r0 = blockIdx.y * 64;
  const int tx = threadIdx.x, ty = threadIdx.y;  // (64, 8)
  for (int rr = ty; rr < 64; rr += 8) {
    const float w = W[(long)(r0 + rr) * DIM + c0 + tx];
    const __bf16 h = (__bf16)w;
    Wh[(long)(r0 + rr) * DIM + c0 + tx] = h;
    t[rr][tx] = h;
  }
  __syncthreads();
  for (int cc = ty; cc < 64; cc += 8)
    Wt[(long)(c0 + cc) * NROWS_W + r0 + tx] = t[tx][cc];
}

// ---------------- GEMM: C[M,N] = A[M,K] * B^T[N,K] + bias (proven R3) --------
// T2 XOR-swizzled LDS (pre-swizzled global source + swizzled ds_read).
// Block remap: 16x32 supertiles so resident blocks share A-rows/B-cols.
__global__ __launch_bounds__(256, 2)
void k_gemm(const __bf16* __restrict__ A, const __bf16* __restrict__ B,
            const float* __restrict__ bias, float* __restrict__ C,
            int M, int N, int Kt) {
  constexpr int BM = 128, BN = 128, BK = 64;
  __shared__ __align__(16) __bf16 sA[BM * BK];
  __shared__ __align__(16) __bf16 sB[BN * BK];

  const int tid = threadIdx.x;
  const int nbn = N / BN;
  int bm, bn;
  if ((M / BM) % 16 == 0 && nbn % 32 == 0) {  // supertile remap
    const int nsbn = nbn / 32;
    const int g = blockIdx.x >> 9, r = blockIdx.x & 511;
    bm = (g / nsbn) * 16 + (r >> 5);
    bn = (g % nsbn) * 32 + (r & 31);
  } else {
    bm = blockIdx.x / nbn;
    bn = blockIdx.x % nbn;
  }
  const int m0 = bm * BM, n0 = bn * BN;
  const int lane = tid & 63, wid = tid >> 6;
  const int wm = wid >> 1, wn = wid & 1;
  const int lr = lane & 15, lk = lane >> 4;
  const int swz = (lr & 7) << 4;

  f32x4 acc[4][4] = {};

  for (int k0 = 0; k0 < Kt; k0 += BK) {
#pragma unroll
    for (int r = 0; r < 4; ++r) {
      const int o = (r * 256 + tid) * 16;
      const int row = o >> 7;
      const int colb = (o & 127) ^ ((row & 7) << 4);
      const long gA = ((long)(m0 + row) * Kt + k0) * 2 + colb;
      const long gB = ((long)(n0 + row) * Kt + k0) * 2 + colb;
      gload_lds16((const char*)A + gA, (char*)sA + o);
      gload_lds16((const char*)B + gB, (char*)sB + o);
    }
    __syncthreads();

#pragma unroll
    for (int kk = 0; kk < 2; ++kk) {
      bf16x8 va[4], vb[4];
      const int kbase = (kk * 64 + lk * 16) ^ swz;
#pragma unroll
      for (int m = 0; m < 4; ++m) {
        const int row = wm * 64 + m * 16 + lr;
        va[m] = *(const bf16x8*)((const char*)sA + row * 128 + kbase);
      }
#pragma unroll
      for (int n = 0; n < 4; ++n) {
        const int row = wn * 64 + n * 16 + lr;
        vb[n] = *(const bf16x8*)((const char*)sB + row * 128 + kbase);
      }
#pragma unroll
      for (int m = 0; m < 4; ++m)
#pragma unroll
        for (int n = 0; n < 4; ++n)
          acc[m][n] = __builtin_amdgcn_mfma_f32_16x16x32_bf16(va[m], vb[n], acc[m][n], 0, 0, 0);
    }
    __syncthreads();
  }

  // C/D layout: col = lane&15, row = (lane>>4)*4 + reg
#pragma unroll
  for (int n = 0; n < 4; ++n) {
    const int col = n0 + wn * 64 + n * 16 + lr;
    const float bv = bias[col];
#pragma unroll
    for (int m = 0; m < 4; ++m) {
      const int r0r = m0 + wm * 64 + m * 16 + lk * 4;
#pragma unroll
      for (int j = 0; j < 4; ++j)
        C[(long)(r0r + j) * N + col] = acc[m][n][j] + bv;
    }
  }
}

// ---------------- float <-> order-preserving u32 ----------------
__device__ __forceinline__ unsigned f2o(float f) {
  unsigned b = __float_as_uint(f);
  return ((int)b < 0) ? ~b : (b | 0x80000000u);
}
__device__ __forceinline__ float o2f(unsigned u) {
  unsigned b = (u & 0x80000000u) ? (u & 0x7FFFFFFFu) : ~u;
  return __uint_as_float(b);
}

// --- per-row: threshold (2 z1 streams) + band from cand list + a1 write ------
__global__ __launch_bounds__(256)
void k_topk4(const float* __restrict__ z1, float* __restrict__ thr,
             unsigned* __restrict__ rowlist, unsigned* __restrict__ rowcnt,
             unsigned* __restrict__ c1, unsigned* __restrict__ bucket,
             unsigned* __restrict__ bcnt, __bf16* __restrict__ a1, int kwant) {
  __shared__ unsigned hist[4096];
  __shared__ float cv[CANDCAP];
  __shared__ unsigned short ci[CANDCAP];
  __shared__ unsigned s_n, s_bin, s_rem, s_wt[4], s_cnt, s_above;
  const int tid = threadIdx.x;
  const int b = blockIdx.x;
  const f32x4* zv = (const f32x4*)(z1 + (long)b * NROWS_W);
  constexpr int NV = NROWS_W / 4;

  // ---- pass A: 4096-bin histogram (top 12 bits) ----
#pragma unroll
  for (int j = 0; j < 16; ++j) hist[tid + j * 256] = 0;
  if (tid == 0) { s_n = 0; s_cnt = 0; s_above = 0; }
  __syncthreads();
  for (int i = tid; i < NV; i += 256) {
    f32x4 v = zv[i];
#pragma unroll
    for (int j = 0; j < 4; ++j) atomicAdd(&hist[f2o(v[j]) >> 20], 1u);
  }
  __syncthreads();
  unsigned p = 0;
#pragma unroll
  for (int j = 0; j < 16; ++j) p += hist[tid * 16 + j];
  unsigned sfx = p;
  const int lane = tid & 63, w = tid >> 6;
#pragma unroll
  for (int off = 1; off < 64; off <<= 1) {
    unsigned o = __shfl_down(sfx, off);
    sfx += (lane + off < 64) ? o : 0u;
  }
  if (lane == 0) s_wt[w] = sfx;
  __syncthreads();
  unsigned above_waves = 0;
  for (int ww = w + 1; ww < 4; ++ww) above_waves += s_wt[ww];
  const unsigned incl = sfx + above_waves;
  const int cnt = __syncthreads_count(incl >= (unsigned)kwant);
  const int tstar = cnt - 1;
  if (tid == tstar) {
    unsigned cum = incl - p;
    int bsel = tid * 16;
    for (int j = 15; j >= 0; --j) {
      const unsigned h = hist[tid * 16 + j];
      if (cum + h >= (unsigned)kwant) { bsel = tid * 16 + j; break; }
      cum += h;
    }
    s_bin = (unsigned)bsel;
    s_rem = (unsigned)kwant - cum;
  }
  __syncthreads();
  const unsigned binsel = s_bin;
  unsigned rem = s_rem;

  // ---- pass B: collect bins binsel-1..binsel+1 with indices ----
  const unsigned blo = (binsel > 0) ? binsel - 1 : 0;
  const unsigned bhi = (binsel < 4095) ? binsel + 1 : 4095;
  for (int i = tid; i < NV; i += 256) {
    f32x4 v = zv[i];
#pragma unroll
    for (int j = 0; j < 4; ++j) {
      const unsigned bin = f2o(v[j]) >> 20;
      if (bin >= blo && bin <= bhi) {
        const unsigned jj = atomicAdd(&s_n, 1u);
        if (jj < CANDCAP) { cv[jj] = v[j]; ci[jj] = (unsigned short)(i * 4 + j); }
      }
    }
  }
  __syncthreads();
  const int n = (s_n < CANDCAP) ? (int)s_n : CANDCAP;

  // ---- in-LDS 20-bit refine over cand members of binsel ----
  unsigned pfx = 0;
#pragma unroll
  for (int pass = 0; pass < 3; ++pass) {
    const int shift = (pass == 0) ? 12 : (pass == 1) ? 4 : 0;
    const int nb = (pass == 2) ? 16 : 256;
    if (tid < 256) hist[tid] = 0;
    __syncthreads();
    for (int i = tid; i < n; i += 256) {
      const unsigned u = f2o(cv[i]);
      if ((u >> 20) != binsel) continue;
      const unsigned v = u & 0xFFFFFu;
      const bool m = (pass == 0) ? true
                     : (pass == 1) ? ((v >> 12) == (pfx >> 12))
                                   : ((v >> 4) == (pfx >> 4));
      if (m) atomicAdd(&hist[(v >> shift) & (nb - 1)], 1u);
    }
    __syncthreads();
    if (tid == 0) {
      unsigned cum = 0;
      int d = nb - 1;
      for (; d > 0; --d) {
        if (cum + hist[d] >= rem) break;
        cum += hist[d];
      }
      s_bin = (unsigned)d;
      s_rem = rem - cum;
    }
    __syncthreads();
    pfx |= (s_bin << shift);
    rem = s_rem;
    __syncthreads();
  }
  const float t = o2f((binsel << 20) | pfx);
  if (tid == 0) thr[b] = t;
  const float hi = t + DELTA, lo = t - DELTA;

  // ---- band members from cand list (no z1 re-scan) ----
  for (int i = tid; i < n; i += 256) {
    const float v = cv[i];
    if (v >= lo && v <= hi) {
      const unsigned idx = ci[i];
      const unsigned jj = atomicAdd(&s_cnt, 1u);
      if (jj < ROWCAP) {
        rowlist[(long)b * ROWCAP + jj] = idx;
        const unsigned pq = atomicAdd(&bcnt[idx], 1u);
        if (pq < HCAP) bucket[(long)idx * HCAP + pq] = ((unsigned)b << 9) | jj;
      }
    }
  }

  // ---- pass C: write a1 (sure-ins only; band patched by k_select), count c1 --
  unsigned my_above = 0;
  bf16x4* av = (bf16x4*)(a1 + (long)b * NROWS_W);
  for (int i = tid; i < NV; i += 256) {
    f32x4 v = zv[i];
    bf16x4 o;
#pragma unroll
    for (int j = 0; j < 4; ++j) {
      const bool in = v[j] > hi;
      my_above += in ? 1u : 0u;
      o[j] = in ? (__bf16)v[j] : (__bf16)0.0f;
    }
    av[i] = o;
  }
  atomicAdd(&s_above, my_above);
  __syncthreads();
  if (tid == 0) {
    rowcnt[b] = (s_cnt < ROWCAP) ? s_cnt : ROWCAP;
    c1[b] = s_above;
  }
}

// ---------------- zero bcnt ----------------
__global__ void k_zero(f32x4* __restrict__ p, int nvec) {
  int i = blockIdx.x * 256 + threadIdx.x;
  if (i < nvec) {
    f32x4 z = {0.f, 0.f, 0.f, 0.f};
    p[i] = z;
  }
}

// -------- h-major exact recompute: fp32 W row in LDS, fp32 x (L3) ----------
__global__ void k_recompute(const float* __restrict__ W, const float* __restrict__ x,
                            const unsigned* __restrict__ bucket,
                            const unsigned* __restrict__ bcnt,
                            float* __restrict__ exact) {
  const int h = blockIdx.x;
  unsigned n = bcnt[h];
  if (n > HCAP) n = HCAP;
  if (n == 0) return;
  __shared__ float wrec[DIM];
  const long wb = (long)h * DIM;
  for (int i = threadIdx.x; i < DIM / 4; i += 256)
    ((f32x4*)wrec)[i] = ((const f32x4*)(W + wb))[i];
  __syncthreads();
  const int w = threadIdx.x >> 6, lane = threadIdx.x & 63;
  for (unsigned e = w; e < n; e += 4) {
    const unsigned ent = bucket[(long)h * HCAP + e];
    const int b = ent >> 9, j = ent & 511;
    const f32x4* xv = (const f32x4*)(x + (long)b * DIM);
    float s = 0.f;
#pragma unroll
    for (int c = 0; c < 16; ++c) {
      const int i4 = c * 64 + lane;
      f32x4 v = xv[i4];
      const float* wr = &wrec[i4 * 4];
#pragma unroll
      for (int q = 0; q < 4; ++q) s += v[q] * wr[q];
    }
#pragma unroll
    for (int m = 32; m; m >>= 1) s += __shfl_xor(s, m);
    if (lane == 0) exact[(long)b * ROWCAP + j] = s;
  }
}

// -- per-row select top (k - C1) among band; patch selected into a1 ----------
__global__ void k_select(const float* __restrict__ exact, const unsigned* __restrict__ rowlist,
                         const unsigned* __restrict__ rowcnt, const unsigned* __restrict__ c1,
                         const float* __restrict__ z1, __bf16* __restrict__ a1) {
  const int b = blockIdx.x;
  const int n = (int)rowcnt[b];
  const int need = KCNT - (int)c1[b];
  __shared__ float vals[ROWCAP];
  const int j = threadIdx.x;  // blockDim == ROWCAP
  vals[j] = (j < n) ? exact[(long)b * ROWCAP + j] : -1e30f;
  __syncthreads();
  if (j < n) {
    const float vj = vals[j];
    int rank = 0;
    for (int i = 0; i < n; ++i) {
      const float vi = vals[i];
      rank += (vi > vj || (vi == vj && i < j)) ? 1 : 0;
    }
    if (rank < need) {
      const unsigned h = rowlist[(long)b * ROWCAP + j];
      const long off = (long)b * NROWS_W + h;
      a1[off] = (__bf16)z1[off];
    }
  }
}

extern "C" void kernel_launch(void* const* d_in, const int* in_sizes, int n_in,
                              void* d_out, int out_size, void* d_ws, size_t ws_size,
                              hipStream_t stream) {
  const float* x     = (const float*)d_in[0];
  const float* W     = (const float*)d_in[1];
  const float* b_enc = (const float*)d_in[2];
  const float* b_dec = (const float*)d_in[3];
  float* out = (float*)d_out;

  const long NW = (long)NROWS_W * DIM;    // 134217728
  const long NX = (long)BATCH * DIM;      // 16777216
  const long NZ = (long)BATCH * NROWS_W;  // 134217728

  char* ws = (char*)d_ws;
  __bf16* Wh = (__bf16*)ws;        // 2*NW  (dead after encoder -> reused as a1)
  __bf16* Wt = Wh + NW;            // 2*NW
  __bf16* xh = Wt + NW;            // 2*NX
  float*  z1 = (float*)(xh + NX);  // 4*NZ
  float*  thr = z1 + NZ;           // 4*BATCH
  char*   sc = (char*)(thr + BATCH);
  unsigned* rowcnt  = (unsigned*)sc;                    // 16 KB
  unsigned* c1      = (unsigned*)(sc + 16384);          // 16 KB
  unsigned* bcnt    = (unsigned*)(sc + 32768);          // 128 KB (zeroed)
  float*    exact   = (float*)(sc + 163840);            // 4 MB
  unsigned* rowlist = (unsigned*)(sc + 4358144);        // 4 MB
  unsigned* bucket  = (unsigned*)(sc + 8552448);        // 8 MB (end ~16.9 MB)
  __bf16* a1 = Wh;

  const size_t needed = (size_t)(4 * NW + 2 * NX) + (size_t)4 * NZ + 4 * BATCH + 17000000;
  if (ws_size < needed) return;

  k_splitw<<<dim3(DIM / 64, NROWS_W / 64), dim3(64, 8), 0, stream>>>(W, Wh, Wt);
  k_cvtx<<<2048, 256, 0, stream>>>(x, xh, (int)(NX / 4));

  // encoder (approx): z1 = xh @ Wh^T + b_enc   [4096 x 32768]
  k_gemm<<<(BATCH / 128) * (NROWS_W / 128), 256, 0, stream>>>(
      xh, Wh, b_enc, z1, BATCH, NROWS_W, DIM);

  k_zero<<<32, 256, 0, stream>>>((f32x4*)bcnt, 131072 / 16);
  k_topk4<<<BATCH, 256, 0, stream>>>(z1, thr, rowlist, rowcnt, c1, bucket, bcnt, a1, KCNT);
  k_recompute<<<NROWS_W, 256, 0, stream>>>(W, x, bucket, bcnt, exact);
  k_select<<<BATCH, ROWCAP, 0, stream>>>(exact, rowlist, rowcnt, c1, z1, a1);

  // decoder: out = a1 @ W + b_dec  (B^T = Wt)
  k_gemm<<<(BATCH / 128) * (DIM / 128), 256, 0, stream>>>(
      a1, Wt, b_dec, out, BATCH, DIM, NROWS_W);
}

// Round 10
// 3154.455 us; speedup vs baseline: 1.2175x; 1.1263x over previous
//
#include <hip/hip_runtime.h>
#include <hip/hip_bf16.h>
#include <stdint.h>

// Sparse autoencoder: z1 = x@W^T + b_enc ; top-k(3276) mask ; z2 = a1@W + b_dec
// Encoder = single fp16 MFMA GEMM (approx, sigma ~4e-4); exact top-k selection
// via fp32 band recompute near the threshold (h-major, W streamed once, fp32 x
// L3-resident). fp16 (10 mantissa bits) vs bf16 shrinks the band ~2.6x and
// drops output absmax ~8x. GEMMs: proven 128^2 m97-structure + T2 swizzle +
// 16x32 supertile remap (four 8-phase variants all measured slower; R4-R8).

#define DIM      4096
#define BATCH    4096
#define NROWS_W  32768
#define KCNT     3276
#define DELTA    0.0025f
#define ROWCAP   256
#define HCAP     64
#define CANDCAP  3584

typedef _Float16 f16x8 __attribute__((ext_vector_type(8)));
typedef _Float16 f16x4 __attribute__((ext_vector_type(4)));
typedef float    f32x4 __attribute__((ext_vector_type(4)));

__device__ __forceinline__ void gload_lds16(const void* g, void* l) {
  __builtin_amdgcn_global_load_lds(
      (const __attribute__((address_space(1))) void*)g,
      (__attribute__((address_space(3))) void*)l, 16, 0, 0);
}

// ---------------- x: fp32 -> fp16 (encoder A operand) ----------------
__global__ void k_cvtx(const float* __restrict__ s, _Float16* __restrict__ hi, int n4) {
  int i = blockIdx.x * 256 + threadIdx.x;
  const int stride = gridDim.x * 256;
  for (; i < n4; i += stride) {
    f32x4 v = ((const f32x4*)s)[i];
    f16x4 h;
#pragma unroll
    for (int j = 0; j < 4; ++j) h[j] = (_Float16)v[j];
    ((f16x4*)hi)[i] = h;
  }
}

// --- fused W convert+transpose: W fp32 -> Wh fp16 [H,D] + Wt fp16 [D,H] ------
// Also zeroes bcnt (blockIdx.y==0 blocks) to save a launch.
__global__ void k_splitw(const float* __restrict__ W, _Float16* __restrict__ Wh,
                         _Float16* __restrict__ Wt, f32x4* __restrict__ bcntv) {
  __shared__ _Float16 t[64][65];
  const int c0 = blockIdx.x * 64, r0 = blockIdx.y * 64;
  const int tx = threadIdx.x, ty = threadIdx.y;  // (64, 8)
  if (blockIdx.y == 0) {
    const int idx = blockIdx.x * 512 + ty * 64 + tx;
    if (idx < 8192) {  // 128 KB bcnt
      f32x4 z = {0.f, 0.f, 0.f, 0.f};
      bcntv[idx] = z;
    }
  }
  for (int rr = ty; rr < 64; rr += 8) {
    const float w = W[(long)(r0 + rr) * DIM + c0 + tx];
    const _Float16 h = (_Float16)w;
    Wh[(long)(r0 + rr) * DIM + c0 + tx] = h;
    t[rr][tx] = h;
  }
  __syncthreads();
  for (int cc = ty; cc < 64; cc += 8)
    Wt[(long)(c0 + cc) * NROWS_W + r0 + tx] = t[tx][cc];
}

// ---------------- GEMM: C[M,N] = A[M,K] * B^T[N,K] + bias (proven R3) --------
// T2 XOR-swizzled LDS (pre-swizzled global source + swizzled ds_read).
// Block remap: 16x32 supertiles so resident blocks share A-rows/B-cols.
__global__ __launch_bounds__(256, 2)
void k_gemm(const _Float16* __restrict__ A, const _Float16* __restrict__ B,
            const float* __restrict__ bias, float* __restrict__ C,
            int M, int N, int Kt) {
  constexpr int BM = 128, BN = 128, BK = 64;
  __shared__ __align__(16) _Float16 sA[BM * BK];
  __shared__ __align__(16) _Float16 sB[BN * BK];

  const int tid = threadIdx.x;
  const int nbn = N / BN;
  int bm, bn;
  if ((M / BM) % 16 == 0 && nbn % 32 == 0) {  // supertile remap
    const int nsbn = nbn / 32;
    const int g = blockIdx.x >> 9, r = blockIdx.x & 511;
    bm = (g / nsbn) * 16 + (r >> 5);
    bn = (g % nsbn) * 32 + (r & 31);
  } else {
    bm = blockIdx.x / nbn;
    bn = blockIdx.x % nbn;
  }
  const int m0 = bm * BM, n0 = bn * BN;
  const int lane = tid & 63, wid = tid >> 6;
  const int wm = wid >> 1, wn = wid & 1;
  const int lr = lane & 15, lk = lane >> 4;
  const int swz = (lr & 7) << 4;

  f32x4 acc[4][4] = {};

  for (int k0 = 0; k0 < Kt; k0 += BK) {
#pragma unroll
    for (int r = 0; r < 4; ++r) {
      const int o = (r * 256 + tid) * 16;
      const int row = o >> 7;
      const int colb = (o & 127) ^ ((row & 7) << 4);
      const long gA = ((long)(m0 + row) * Kt + k0) * 2 + colb;
      const long gB = ((long)(n0 + row) * Kt + k0) * 2 + colb;
      gload_lds16((const char*)A + gA, (char*)sA + o);
      gload_lds16((const char*)B + gB, (char*)sB + o);
    }
    __syncthreads();

#pragma unroll
    for (int kk = 0; kk < 2; ++kk) {
      f16x8 va[4], vb[4];
      const int kbase = (kk * 64 + lk * 16) ^ swz;
#pragma unroll
      for (int m = 0; m < 4; ++m) {
        const int row = wm * 64 + m * 16 + lr;
        va[m] = *(const f16x8*)((const char*)sA + row * 128 + kbase);
      }
#pragma unroll
      for (int n = 0; n < 4; ++n) {
        const int row = wn * 64 + n * 16 + lr;
        vb[n] = *(const f16x8*)((const char*)sB + row * 128 + kbase);
      }
#pragma unroll
      for (int m = 0; m < 4; ++m)
#pragma unroll
        for (int n = 0; n < 4; ++n)
          acc[m][n] = __builtin_amdgcn_mfma_f32_16x16x32_f16(va[m], vb[n], acc[m][n], 0, 0, 0);
    }
    __syncthreads();
  }

  // C/D layout: col = lane&15, row = (lane>>4)*4 + reg
#pragma unroll
  for (int n = 0; n < 4; ++n) {
    const int col = n0 + wn * 64 + n * 16 + lr;
    const float bv = bias[col];
#pragma unroll
    for (int m = 0; m < 4; ++m) {
      const int r0r = m0 + wm * 64 + m * 16 + lk * 4;
#pragma unroll
      for (int j = 0; j < 4; ++j)
        C[(long)(r0r + j) * N + col] = acc[m][n][j] + bv;
    }
  }
}

// ---------------- float <-> order-preserving u32 ----------------
__device__ __forceinline__ unsigned f2o(float f) {
  unsigned b = __float_as_uint(f);
  return ((int)b < 0) ? ~b : (b | 0x80000000u);
}
__device__ __forceinline__ float o2f(unsigned u) {
  unsigned b = (u & 0x80000000u) ? (u & 0x7FFFFFFFu) : ~u;
  return __uint_as_float(b);
}

// --- per-row: threshold (2 z1 streams) + band from cand list + a1 write ------
__global__ __launch_bounds__(256)
void k_topk4(const float* __restrict__ z1, float* __restrict__ thr,
             unsigned* __restrict__ rowlist, unsigned* __restrict__ rowcnt,
             unsigned* __restrict__ c1, unsigned* __restrict__ bucket,
             unsigned* __restrict__ bcnt, _Float16* __restrict__ a1, int kwant) {
  __shared__ unsigned hist[4096];
  __shared__ float cv[CANDCAP];
  __shared__ unsigned short ci[CANDCAP];
  __shared__ unsigned s_n, s_bin, s_rem, s_wt[4], s_cnt, s_above;
  const int tid = threadIdx.x;
  const int b = blockIdx.x;
  const f32x4* zv = (const f32x4*)(z1 + (long)b * NROWS_W);
  constexpr int NV = NROWS_W / 4;

  // ---- pass A: 4096-bin histogram (top 12 bits) ----
#pragma unroll
  for (int j = 0; j < 16; ++j) hist[tid + j * 256] = 0;
  if (tid == 0) { s_n = 0; s_cnt = 0; s_above = 0; }
  __syncthreads();
  for (int i = tid; i < NV; i += 256) {
    f32x4 v = zv[i];
#pragma unroll
    for (int j = 0; j < 4; ++j) atomicAdd(&hist[f2o(v[j]) >> 20], 1u);
  }
  __syncthreads();
  unsigned p = 0;
#pragma unroll
  for (int j = 0; j < 16; ++j) p += hist[tid * 16 + j];
  unsigned sfx = p;
  const int lane = tid & 63, w = tid >> 6;
#pragma unroll
  for (int off = 1; off < 64; off <<= 1) {
    unsigned o = __shfl_down(sfx, off);
    sfx += (lane + off < 64) ? o : 0u;
  }
  if (lane == 0) s_wt[w] = sfx;
  __syncthreads();
  unsigned above_waves = 0;
  for (int ww = w + 1; ww < 4; ++ww) above_waves += s_wt[ww];
  const unsigned incl = sfx + above_waves;
  const int cnt = __syncthreads_count(incl >= (unsigned)kwant);
  const int tstar = cnt - 1;
  if (tid == tstar) {
    unsigned cum = incl - p;
    int bsel = tid * 16;
    for (int j = 15; j >= 0; --j) {
      const unsigned h = hist[tid * 16 + j];
      if (cum + h >= (unsigned)kwant) { bsel = tid * 16 + j; break; }
      cum += h;
    }
    s_bin = (unsigned)bsel;
    s_rem = (unsigned)kwant - cum;
  }
  __syncthreads();
  const unsigned binsel = s_bin;
  unsigned rem = s_rem;

  // ---- pass B: collect bins binsel-1..binsel+1 with indices ----
  const unsigned blo = (binsel > 0) ? binsel - 1 : 0;
  const unsigned bhi = (binsel < 4095) ? binsel + 1 : 4095;
  for (int i = tid; i < NV; i += 256) {
    f32x4 v = zv[i];
#pragma unroll
    for (int j = 0; j < 4; ++j) {
      const unsigned bin = f2o(v[j]) >> 20;
      if (bin >= blo && bin <= bhi) {
        const unsigned jj = atomicAdd(&s_n, 1u);
        if (jj < CANDCAP) { cv[jj] = v[j]; ci[jj] = (unsigned short)(i * 4 + j); }
      }
    }
  }
  __syncthreads();
  const int n = (s_n < CANDCAP) ? (int)s_n : CANDCAP;

  // ---- in-LDS 20-bit refine over cand members of binsel ----
  unsigned pfx = 0;
#pragma unroll
  for (int pass = 0; pass < 3; ++pass) {
    const int shift = (pass == 0) ? 12 : (pass == 1) ? 4 : 0;
    const int nb = (pass == 2) ? 16 : 256;
    if (tid < 256) hist[tid] = 0;
    __syncthreads();
    for (int i = tid; i < n; i += 256) {
      const unsigned u = f2o(cv[i]);
      if ((u >> 20) != binsel) continue;
      const unsigned v = u & 0xFFFFFu;
      const bool m = (pass == 0) ? true
                     : (pass == 1) ? ((v >> 12) == (pfx >> 12))
                                   : ((v >> 4) == (pfx >> 4));
      if (m) atomicAdd(&hist[(v >> shift) & (nb - 1)], 1u);
    }
    __syncthreads();
    if (tid == 0) {
      unsigned cum = 0;
      int d = nb - 1;
      for (; d > 0; --d) {
        if (cum + hist[d] >= rem) break;
        cum += hist[d];
      }
      s_bin = (unsigned)d;
      s_rem = rem - cum;
    }
    __syncthreads();
    pfx |= (s_bin << shift);
    rem = s_rem;
    __syncthreads();
  }
  const float t = o2f((binsel << 20) | pfx);
  if (tid == 0) thr[b] = t;
  const float hi = t + DELTA, lo = t - DELTA;

  // ---- band members from cand list (no z1 re-scan) ----
  for (int i = tid; i < n; i += 256) {
    const float v = cv[i];
    if (v >= lo && v <= hi) {
      const unsigned idx = ci[i];
      const unsigned jj = atomicAdd(&s_cnt, 1u);
      if (jj < ROWCAP) {
        rowlist[(long)b * ROWCAP + jj] = idx;
        const unsigned pq = atomicAdd(&bcnt[idx], 1u);
        if (pq < HCAP) bucket[(long)idx * HCAP + pq] = ((unsigned)b << 9) | jj;
      }
    }
  }

  // ---- pass C: write a1 (sure-ins only; band patched by k_select), count c1 --
  unsigned my_above = 0;
  f16x4* av = (f16x4*)(a1 + (long)b * NROWS_W);
  for (int i = tid; i < NV; i += 256) {
    f32x4 v = zv[i];
    f16x4 o;
#pragma unroll
    for (int j = 0; j < 4; ++j) {
      const bool in = v[j] > hi;
      my_above += in ? 1u : 0u;
      o[j] = in ? (_Float16)v[j] : (_Float16)0.0f;
    }
    av[i] = o;
  }
  atomicAdd(&s_above, my_above);
  __syncthreads();
  if (tid == 0) {
    rowcnt[b] = (s_cnt < ROWCAP) ? s_cnt : ROWCAP;
    c1[b] = s_above;
  }
}

// -------- h-major exact recompute: fp32 W row in LDS, fp32 x (L3) ----------
__global__ void k_recompute(const float* __restrict__ W, const float* __restrict__ x,
                            const unsigned* __restrict__ bucket,
                            const unsigned* __restrict__ bcnt,
                            float* __restrict__ exact) {
  const int h = blockIdx.x;
  unsigned n = bcnt[h];
  if (n > HCAP) n = HCAP;
  if (n == 0) return;
  __shared__ float wrec[DIM];
  const long wb = (long)h * DIM;
  for (int i = threadIdx.x; i < DIM / 4; i += 256)
    ((f32x4*)wrec)[i] = ((const f32x4*)(W + wb))[i];
  __syncthreads();
  const int w = threadIdx.x >> 6, lane = threadIdx.x & 63;
  for (unsigned e = w; e < n; e += 4) {
    const unsigned ent = bucket[(long)h * HCAP + e];
    const int b = ent >> 9, j = ent & 511;
    const f32x4* xv = (const f32x4*)(x + (long)b * DIM);
    float s = 0.f;
#pragma unroll
    for (int c = 0; c < 16; ++c) {
      const int i4 = c * 64 + lane;
      f32x4 v = xv[i4];
      const float* wr = &wrec[i4 * 4];
#pragma unroll
      for (int q = 0; q < 4; ++q) s += v[q] * wr[q];
    }
#pragma unroll
    for (int m = 32; m; m >>= 1) s += __shfl_xor(s, m);
    if (lane == 0) exact[(long)b * ROWCAP + j] = s;
  }
}

// -- per-row select top (k - C1) among band; patch selected into a1 ----------
__global__ void k_select(const float* __restrict__ exact, const unsigned* __restrict__ rowlist,
                         const unsigned* __restrict__ rowcnt, const unsigned* __restrict__ c1,
                         const float* __restrict__ z1, _Float16* __restrict__ a1) {
  const int b = blockIdx.x;
  const int n = (int)rowcnt[b];
  const int need = KCNT - (int)c1[b];
  __shared__ float vals[ROWCAP];
  const int j = threadIdx.x;  // blockDim == ROWCAP
  vals[j] = (j < n) ? exact[(long)b * ROWCAP + j] : -1e30f;
  __syncthreads();
  if (j < n) {
    const float vj = vals[j];
    int rank = 0;
    for (int i = 0; i < n; ++i) {
      const float vi = vals[i];
      rank += (vi > vj || (vi == vj && i < j)) ? 1 : 0;
    }
    if (rank < need) {
      const unsigned h = rowlist[(long)b * ROWCAP + j];
      const long off = (long)b * NROWS_W + h;
      a1[off] = (_Float16)z1[off];
    }
  }
}

extern "C" void kernel_launch(void* const* d_in, const int* in_sizes, int n_in,
                              void* d_out, int out_size, void* d_ws, size_t ws_size,
                              hipStream_t stream) {
  const float* x     = (const float*)d_in[0];
  const float* W     = (const float*)d_in[1];
  const float* b_enc = (const float*)d_in[2];
  const float* b_dec = (const float*)d_in[3];
  float* out = (float*)d_out;

  const long NW = (long)NROWS_W * DIM;    // 134217728
  const long NX = (long)BATCH * DIM;      // 16777216
  const long NZ = (long)BATCH * NROWS_W;  // 134217728

  char* ws = (char*)d_ws;
  _Float16* Wh = (_Float16*)ws;    // 2*NW  (dead after encoder -> reused as a1)
  _Float16* Wt = Wh + NW;          // 2*NW
  _Float16* xh = Wt + NW;          // 2*NX
  float*  z1 = (float*)(xh + NX);  // 4*NZ
  float*  thr = z1 + NZ;           // 4*BATCH
  char*   sc = (char*)(thr + BATCH);
  unsigned* rowcnt  = (unsigned*)sc;                    // 16 KB
  unsigned* c1      = (unsigned*)(sc + 16384);          // 16 KB
  unsigned* bcnt    = (unsigned*)(sc + 32768);          // 128 KB (zeroed in splitw)
  float*    exact   = (float*)(sc + 163840);            // 4 MB
  unsigned* rowlist = (unsigned*)(sc + 4358144);        // 4 MB
  unsigned* bucket  = (unsigned*)(sc + 8552448);        // 8 MB (end ~16.9 MB)
  _Float16* a1 = Wh;

  const size_t needed = (size_t)(4 * NW + 2 * NX) + (size_t)4 * NZ + 4 * BATCH + 17000000;
  if (ws_size < needed) return;

  k_splitw<<<dim3(DIM / 64, NROWS_W / 64), dim3(64, 8), 0, stream>>>(W, Wh, Wt, (f32x4*)bcnt);
  k_cvtx<<<2048, 256, 0, stream>>>(x, xh, (int)(NX / 4));

  // encoder (approx): z1 = xh @ Wh^T + b_enc   [4096 x 32768]
  k_gemm<<<(BATCH / 128) * (NROWS_W / 128), 256, 0, stream>>>(
      xh, Wh, b_enc, z1, BATCH, NROWS_W, DIM);

  k_topk4<<<BATCH, 256, 0, stream>>>(z1, thr, rowlist, rowcnt, c1, bucket, bcnt, a1, KCNT);
  k_recompute<<<NROWS_W, 256, 0, stream>>>(W, x, bucket, bcnt, exact);
  k_select<<<BATCH, ROWCAP, 0, stream>>>(exact, rowlist, rowcnt, c1, z1, a1);

  // decoder: out = a1 @ W + b_dec  (B^T = Wt)
  k_gemm<<<(BATCH / 128) * (DIM / 128), 256, 0, stream>>>(
      a1, Wt, b_dec, out, BATCH, DIM, NROWS_W);
}